// Round 1
// baseline (3875.534 us; speedup 1.0000x reference)
//
#include <hip/hip_runtime.h>
#include <cfloat>
#include <math.h>

#define B_      16
#define N_TOK   1029
#define C_      1024
#define H_      16
#define D_      64
#define PREFIX  5
#define M_ROWS  (B_ * N_TOK)                       // 16464
#define HEAD_SLAB ((size_t)B_ * H_ * N_TOK * D_)   // 16,859,136 floats per q/k/v buffer

// ---------------------------------------------------------------------------
// GEMM: out = A @ W^T + bias.  A [M x K] row-major, W [Ncols x K] row-major.
// scatter==0: out[m*Ncols + c]
// scatter==1: qkv scatter into q/k/v [B,H,N,D] slabs at out + which*HEAD_SLAB
// BM=BN=64, BK=32, 256 threads, 4x4 micro-tile per thread.
// LDS tiles stored k-major with XOR swizzle so inner loop is 2x ds_read_b128.
// ---------------------------------------------------------------------------
__device__ __forceinline__ int swz(int k, int m) {
    // element (k, m) of a [32][64] k-major tile, chunk-XOR-swizzled
    return k * 64 + ((((m >> 2) ^ (k & 15)) << 2) | (m & 3));
}

__global__ __launch_bounds__(256)
void gemm_kernel(const float* __restrict__ A, const float* __restrict__ W,
                 const float* __restrict__ bias, float* __restrict__ out,
                 int M, int Ncols, int K, int scatter)
{
    __shared__ __align__(16) float As[32 * 64];
    __shared__ __align__(16) float Ws[32 * 64];

    const int tid = threadIdx.x;
    const int tq  = tid >> 4;     // 0..15 -> A-row group
    const int tk  = tid & 15;     // 0..15 -> W-row (=output col) group
    const int r0  = blockIdx.y * 64;
    const int c0  = blockIdx.x * 64;

    float acc[4][4];
#pragma unroll
    for (int i = 0; i < 4; ++i)
#pragma unroll
        for (int j = 0; j < 4; ++j) acc[i][j] = 0.f;

    const int srow = tid >> 3;        // 0..31
    const int sk4  = (tid & 7) << 2;  // 0,4,...,28

    for (int k0 = 0; k0 < K; k0 += 32) {
#pragma unroll
        for (int t = 0; t < 2; ++t) {
            const int row = srow + t * 32;   // 0..63
            const int gm  = r0 + row;
            float4 av = make_float4(0.f, 0.f, 0.f, 0.f);
            if (gm < M) av = *(const float4*)(A + (size_t)gm * K + (k0 + sk4));
            As[swz(sk4 + 0, row)] = av.x;
            As[swz(sk4 + 1, row)] = av.y;
            As[swz(sk4 + 2, row)] = av.z;
            As[swz(sk4 + 3, row)] = av.w;
            const float4 wv = *(const float4*)(W + (size_t)(c0 + row) * K + (k0 + sk4));
            Ws[swz(sk4 + 0, row)] = wv.x;
            Ws[swz(sk4 + 1, row)] = wv.y;
            Ws[swz(sk4 + 2, row)] = wv.z;
            Ws[swz(sk4 + 3, row)] = wv.w;
        }
        __syncthreads();
#pragma unroll 8
        for (int kk = 0; kk < 32; ++kk) {
            const float4 a4 = *(const float4*)&As[kk * 64 + ((tq ^ (kk & 15)) << 2)];
            const float4 w4 = *(const float4*)&Ws[kk * 64 + ((tk ^ (kk & 15)) << 2)];
            const float aa[4] = {a4.x, a4.y, a4.z, a4.w};
            const float ww[4] = {w4.x, w4.y, w4.z, w4.w};
#pragma unroll
            for (int i = 0; i < 4; ++i)
#pragma unroll
                for (int j = 0; j < 4; ++j)
                    acc[i][j] = fmaf(aa[i], ww[j], acc[i][j]);
        }
        __syncthreads();
    }

    const float4 bv = *(const float4*)(bias + c0 + 4 * tk);
    const float bb[4] = {bv.x, bv.y, bv.z, bv.w};

    if (!scatter) {
#pragma unroll
        for (int i = 0; i < 4; ++i) {
            const int gm = r0 + 4 * tq + i;
            if (gm < M) {
                const float4 v = make_float4(acc[i][0] + bb[0], acc[i][1] + bb[1],
                                             acc[i][2] + bb[2], acc[i][3] + bb[3]);
                *(float4*)(out + (size_t)gm * Ncols + c0 + 4 * tk) = v;
            }
        }
    } else {
        const int which = c0 >> 10;          // 0=q 1=k 2=v (64-col tile never straddles)
        const int h     = (c0 >> 6) & 15;
#pragma unroll
        for (int i = 0; i < 4; ++i) {
            const int gm = r0 + 4 * tq + i;
            if (gm < M) {
                const int b = gm / N_TOK;
                const int n = gm - b * N_TOK;
                const size_t dst = (size_t)which * HEAD_SLAB +
                                   (((size_t)(b * H_ + h)) * N_TOK + n) * 64 + 4 * tk;
                const float4 v = make_float4(acc[i][0] + bb[0], acc[i][1] + bb[1],
                                             acc[i][2] + bb[2], acc[i][3] + bb[3]);
                *(float4*)(out + dst) = v;
            }
        }
    }
}

// ---------------------------------------------------------------------------
// In-place RoPE on q/k [B*H, N, D] for tokens n >= PREFIX; also folds the
// attention score scale (1/sqrt(D) = 0.125) into q for ALL tokens.
// One thread per (bh, n, d) with d in [0,32): owns the (d, d+32) pair.
// ---------------------------------------------------------------------------
__global__ __launch_bounds__(256)
void rope_kernel(float* __restrict__ qb, float* __restrict__ kb,
                 const float* __restrict__ sin_, const float* __restrict__ cos_)
{
    const int idx = blockIdx.x * 256 + threadIdx.x;
    const int total = B_ * H_ * N_TOK * 32;
    if (idx >= total) return;
    const int d   = idx & 31;
    const int tmp = idx >> 5;
    const int n   = tmp % N_TOK;
    const int bh  = tmp / N_TOK;

    const size_t base = ((size_t)bh * N_TOK + n) * 64;
    float* q = qb + base;
    const float SCALE = 0.125f;

    if (n < PREFIX) {
        q[d]      *= SCALE;
        q[d + 32] *= SCALE;
        return;
    }
    const int r = n - PREFIX;
    const float c1 = cos_[r * 64 + d];
    const float c2 = cos_[r * 64 + d + 32];
    const float s1 = sin_[r * 64 + d];
    const float s2 = sin_[r * 64 + d + 32];

    const float q1 = q[d], q2 = q[d + 32];
    q[d]      = (q1 * c1 - q2 * s1) * SCALE;
    q[d + 32] = (q2 * c2 + q1 * s2) * SCALE;

    float* k = kb + base;
    const float k1 = k[d], k2 = k[d + 32];
    k[d]      = k1 * c1 - k2 * s1;
    k[d + 32] = k2 * c2 + k1 * s2;
}

// ---------------------------------------------------------------------------
// Flash attention, fp32. One block per (q-tile of 64, bh). 256 threads.
// Q and K staged TRANSPOSED ([d][token], stride 68) so both the score loop
// and the PV loop are outer-product: 2x ds_read_b128 -> 16 FMA.
// Online softmax; m/l replicated across the 16 lanes sharing a q-row group.
// Output written as [B, N, H, D] (row-major [M_ROWS, C]) for the proj GEMM.
// ---------------------------------------------------------------------------
__global__ __launch_bounds__(256)
void attn_kernel(const float* __restrict__ Qb, const float* __restrict__ Kb,
                 const float* __restrict__ Vb, float* __restrict__ Ob)
{
    __shared__ __align__(16) float Qt[64 * 68];  // [d][q]
    __shared__ __align__(16) float Kt[64 * 68];  // [d][k]
    __shared__ __align__(16) float Vs[64 * 68];  // [k][d]
    __shared__ __align__(16) float Ps[64 * 65];  // [q][k]

    const int tid = threadIdx.x;
    const int tq  = tid >> 4;    // q-row group 0..15
    const int tk  = tid & 15;    // key / out-dim group 0..15
    const int bh  = blockIdx.y;
    const int q0  = blockIdx.x * 64;

    const float* Q  = Qb + (size_t)bh * N_TOK * 64;
    const float* Kp = Kb + (size_t)bh * N_TOK * 64;
    const float* Vp = Vb + (size_t)bh * N_TOK * 64;

    // stage Q transposed (once)
#pragma unroll
    for (int t = 0; t < 4; ++t) {
        const int f   = tid + t * 256;     // 0..1023 float4s
        const int row = f >> 4;
        const int c4  = (f & 15) << 2;
        const int gq  = q0 + row;
        float4 v = make_float4(0.f, 0.f, 0.f, 0.f);
        if (gq < N_TOK) v = *(const float4*)(Q + (size_t)gq * 64 + c4);
        Qt[(c4 + 0) * 68 + row] = v.x;
        Qt[(c4 + 1) * 68 + row] = v.y;
        Qt[(c4 + 2) * 68 + row] = v.z;
        Qt[(c4 + 3) * 68 + row] = v.w;
    }

    float o[4][4];
    float m_i[4], l_i[4];
#pragma unroll
    for (int i = 0; i < 4; ++i) {
        m_i[i] = -FLT_MAX;
        l_i[i] = 0.f;
#pragma unroll
        for (int j = 0; j < 4; ++j) o[i][j] = 0.f;
    }

    for (int kt = 0; kt < 17; ++kt) {
        const int k0 = kt * 64;
        __syncthreads();   // staging below overwrites Kt/Vs read by prev PV; also fences Qt on iter 0
#pragma unroll
        for (int t = 0; t < 4; ++t) {
            const int f   = tid + t * 256;
            const int row = f >> 4;
            const int c4  = (f & 15) << 2;
            const int gk  = k0 + row;
            float4 kv = make_float4(0.f, 0.f, 0.f, 0.f);
            float4 vv = make_float4(0.f, 0.f, 0.f, 0.f);
            if (gk < N_TOK) {
                kv = *(const float4*)(Kp + (size_t)gk * 64 + c4);
                vv = *(const float4*)(Vp + (size_t)gk * 64 + c4);
            }
            Kt[(c4 + 0) * 68 + row] = kv.x;
            Kt[(c4 + 1) * 68 + row] = kv.y;
            Kt[(c4 + 2) * 68 + row] = kv.z;
            Kt[(c4 + 3) * 68 + row] = kv.w;
            *(float4*)&Vs[row * 68 + c4] = vv;
        }
        __syncthreads();

        float s[4][4];
#pragma unroll
        for (int i = 0; i < 4; ++i)
#pragma unroll
            for (int j = 0; j < 4; ++j) s[i][j] = 0.f;

#pragma unroll 8
        for (int d = 0; d < 64; ++d) {
            const float4 q4 = *(const float4*)&Qt[d * 68 + 4 * tq];
            const float4 k4 = *(const float4*)&Kt[d * 68 + 4 * tk];
            const float qa[4] = {q4.x, q4.y, q4.z, q4.w};
            const float ka[4] = {k4.x, k4.y, k4.z, k4.w};
#pragma unroll
            for (int i = 0; i < 4; ++i)
#pragma unroll
                for (int j = 0; j < 4; ++j)
                    s[i][j] = fmaf(qa[i], ka[j], s[i][j]);
        }

        // mask out-of-range keys (only the last tile has any)
        if (k0 + 64 > N_TOK) {
#pragma unroll
            for (int j = 0; j < 4; ++j) {
                if (k0 + 4 * tk + j >= N_TOK) {
#pragma unroll
                    for (int i = 0; i < 4; ++i) s[i][j] = -FLT_MAX;
                }
            }
        }

        // online softmax update (per q-row; reduce over the 16 tk lanes)
#pragma unroll
        for (int i = 0; i < 4; ++i) {
            float mt = fmaxf(fmaxf(s[i][0], s[i][1]), fmaxf(s[i][2], s[i][3]));
            mt = fmaxf(mt, __shfl_xor(mt, 1));
            mt = fmaxf(mt, __shfl_xor(mt, 2));
            mt = fmaxf(mt, __shfl_xor(mt, 4));
            mt = fmaxf(mt, __shfl_xor(mt, 8));
            const float mnew  = fmaxf(m_i[i], mt);
            const float alpha = expf(m_i[i] - mnew);
            float rs = 0.f;
#pragma unroll
            for (int j = 0; j < 4; ++j) {
                const float p = expf(s[i][j] - mnew);
                s[i][j] = p;
                rs += p;
            }
            rs += __shfl_xor(rs, 1);
            rs += __shfl_xor(rs, 2);
            rs += __shfl_xor(rs, 4);
            rs += __shfl_xor(rs, 8);
            l_i[i] = l_i[i] * alpha + rs;
            m_i[i] = mnew;
#pragma unroll
            for (int j = 0; j < 4; ++j) o[i][j] *= alpha;
        }

        // publish probabilities
#pragma unroll
        for (int i = 0; i < 4; ++i)
#pragma unroll
            for (int j = 0; j < 4; ++j)
                Ps[(4 * tq + i) * 65 + 4 * tk + j] = s[i][j];
        __syncthreads();

        // PV: o[q][d] += P[q][key] * V[key][d]
#pragma unroll 8
        for (int key = 0; key < 64; ++key) {
            const float4 v4 = *(const float4*)&Vs[key * 68 + 4 * tk];
            const float va[4] = {v4.x, v4.y, v4.z, v4.w};
            const float p0 = Ps[(4 * tq + 0) * 65 + key];
            const float p1 = Ps[(4 * tq + 1) * 65 + key];
            const float p2 = Ps[(4 * tq + 2) * 65 + key];
            const float p3 = Ps[(4 * tq + 3) * 65 + key];
#pragma unroll
            for (int j = 0; j < 4; ++j) {
                o[0][j] = fmaf(p0, va[j], o[0][j]);
                o[1][j] = fmaf(p1, va[j], o[1][j]);
                o[2][j] = fmaf(p2, va[j], o[2][j]);
                o[3][j] = fmaf(p3, va[j], o[3][j]);
            }
        }
    }

    // epilogue: normalize and store as [B, N, H, D]
    const int b = bh >> 4;
    const int h = bh & 15;
#pragma unroll
    for (int i = 0; i < 4; ++i) {
        const int gq = q0 + 4 * tq + i;
        if (gq < N_TOK) {
            const float inv = 1.0f / l_i[i];
            const float4 v = make_float4(o[i][0] * inv, o[i][1] * inv,
                                         o[i][2] * inv, o[i][3] * inv);
            *(float4*)(Ob + (((size_t)(b * N_TOK + gq)) * H_ + h) * D_ + 4 * tk) = v;
        }
    }
}

// ---------------------------------------------------------------------------
extern "C" void kernel_launch(void* const* d_in, const int* in_sizes, int n_in,
                              void* d_out, int out_size, void* d_ws, size_t ws_size,
                              hipStream_t stream)
{
    const float* x        = (const float*)d_in[0];
    const float* rope_sin = (const float*)d_in[1];
    const float* rope_cos = (const float*)d_in[2];
    const float* W_qkv    = (const float*)d_in[3];
    const float* b_qkv    = (const float*)d_in[4];
    const float* W_proj   = (const float*)d_in[5];
    const float* b_proj   = (const float*)d_in[6];
    float* out = (float*)d_out;

    // ws layout: q | k | v | attn   (4 * 16,859,136 floats = 269.7 MB)
    float* q_buf = (float*)d_ws;
    float* k_buf = q_buf + HEAD_SLAB;
    float* v_buf = q_buf + 2 * HEAD_SLAB;
    float* attn  = q_buf + 3 * HEAD_SLAB;

    // 1) QKV projection, scattered into q/k/v [B,H,N,D]
    {
        dim3 grid(3 * C_ / 64, (M_ROWS + 63) / 64);
        gemm_kernel<<<grid, 256, 0, stream>>>(x, W_qkv, b_qkv, q_buf,
                                              M_ROWS, 3 * C_, C_, 1);
    }
    // 2) RoPE in-place on q/k (+ fold 1/sqrt(D) into q)
    {
        const int total = B_ * H_ * N_TOK * 32;
        rope_kernel<<<(total + 255) / 256, 256, 0, stream>>>(q_buf, k_buf,
                                                             rope_sin, rope_cos);
    }
    // 3) Flash attention -> attn [B, N, H, D]
    {
        dim3 grid((N_TOK + 63) / 64, B_ * H_);
        attn_kernel<<<grid, 256, 0, stream>>>(q_buf, k_buf, v_buf, attn);
    }
    // 4) Output projection -> d_out
    {
        dim3 grid(C_ / 64, (M_ROWS + 63) / 64);
        gemm_kernel<<<grid, 256, 0, stream>>>(attn, W_proj, b_proj, out,
                                              M_ROWS, C_, C_, 0);
    }
}

// Round 3
// 1998.521 us; speedup vs baseline: 1.9392x; 1.9392x over previous
//
#include <hip/hip_runtime.h>
#include <cfloat>
#include <math.h>

#define B_      16
#define N_TOK   1029
#define C_      1024
#define H_      16
#define D_      64
#define PREFIX  5
#define M_ROWS  (B_ * N_TOK)                       // 16464
#define HEAD_SLAB ((size_t)B_ * H_ * N_TOK * D_)   // 16,859,136 floats per q/k/v buffer

typedef __attribute__((ext_vector_type(8))) short bf16x8;
typedef __attribute__((ext_vector_type(4))) float f32x4;

// ---- bf16 helpers (RNE), raw ushort storage ------------------------------
__device__ __forceinline__ unsigned short f2bf(float f) {
    unsigned u = __float_as_uint(f);
    u += 0x7fffu + ((u >> 16) & 1u);          // round-to-nearest-even
    return (unsigned short)(u >> 16);
}
__device__ __forceinline__ float bf2f(unsigned short h) {
    return __uint_as_float(((unsigned)h) << 16);
}

// ---------------------------------------------------------------------------
// Split fp32 array into bf16 hi + bf16 lo (residual). n4 = count/4.
// ---------------------------------------------------------------------------
__global__ __launch_bounds__(256)
void split_kernel(const float* __restrict__ in, unsigned short* __restrict__ hi,
                  unsigned short* __restrict__ lo, int n4)
{
    const int i = blockIdx.x * 256 + threadIdx.x;
    if (i >= n4) return;
    const float4 v = ((const float4*)in)[i];
    ushort4 h, l;
    h.x = f2bf(v.x); l.x = f2bf(v.x - bf2f(h.x));
    h.y = f2bf(v.y); l.y = f2bf(v.y - bf2f(h.y));
    h.z = f2bf(v.z); l.z = f2bf(v.z - bf2f(h.z));
    h.w = f2bf(v.w); l.w = f2bf(v.w - bf2f(h.w));
    ((ushort4*)hi)[i] = h;
    ((ushort4*)lo)[i] = l;
}

// ---------------------------------------------------------------------------
// MFMA GEMM: out = (Ahi+Alo) @ (Whi+Wlo)^T + bias, dropping lo*lo.
// A [M x K], W [Ncols x K], both split into bf16 hi/lo, row-major.
// 128x128 tile, BK=32, 256 threads = 4 waves (2x2), 16x16x32 bf16 MFMA,
// 4x4 MFMA tiles per wave, global_load_lds width-16 staging (1 tile/wave).
// scatter==1: QKV scatter into q/k/v [B,H,N,D] slabs at out + which*HEAD_SLAB.
// ---------------------------------------------------------------------------
__global__ __launch_bounds__(256)
void gemm_mfma(const unsigned short* __restrict__ Ahi, const unsigned short* __restrict__ Alo,
               const unsigned short* __restrict__ Whi, const unsigned short* __restrict__ Wlo,
               const float* __restrict__ bias, float* __restrict__ out,
               int M, int Ncols, int K, int scatter)
{
    __shared__ unsigned short lds[4][128 * 32];   // Ahi | Alo | Whi | Wlo tiles, 8KB each

    const int tid  = threadIdx.x;
    const int wave = tid >> 6;
    const int lane = tid & 63;
    const int bx = blockIdx.x, by = blockIdx.y;
    const int wm = wave >> 1, wn = wave & 1;

    f32x4 acc[4][4];
#pragma unroll
    for (int mi = 0; mi < 4; ++mi)
#pragma unroll
        for (int ni = 0; ni < 4; ++ni)
            acc[mi][ni] = (f32x4){0.f, 0.f, 0.f, 0.f};

    // staging role: wave w stages tile w
    const unsigned short* src = (wave == 0) ? Ahi : (wave == 1) ? Alo
                              : (wave == 2) ? Whi : Wlo;
    const bool isA  = (wave < 2);
    const int  row0 = isA ? by * 128 : bx * 128;
    const int  rlo  = lane >> 2;          // 0..15: row within 16-row group
    const int  koff = (lane & 3) << 3;    // 0,8,16,24 bf16 elements

    const int lm = lane & 15;             // MFMA row/col within 16-tile
    const int q8 = (lane >> 4) << 3;      // k offset = quad*8

    for (int k0 = 0; k0 < K; k0 += 32) {
        __syncthreads();   // previous iteration's LDS reads done
#pragma unroll
        for (int i = 0; i < 8; ++i) {
            int grow = row0 + i * 16 + rlo;
            if (isA && grow > M - 1) grow = M - 1;   // clamp OOB rows (results discarded)
            const unsigned short* g = src + (size_t)grow * K + k0 + koff;
            __builtin_amdgcn_global_load_lds(
                (__attribute__((address_space(1))) void*)g,
                (__attribute__((address_space(3))) void*)&lds[wave][i * 512],
                16, 0, 0);
        }
        __syncthreads();   // drains vmcnt + barrier: tiles visible

        bf16x8 ah[4], al[4], bh[4], bl[4];
#pragma unroll
        for (int mi = 0; mi < 4; ++mi) {
            const int r = wm * 64 + mi * 16 + lm;
            ah[mi] = *(const bf16x8*)&lds[0][r * 32 + q8];
            al[mi] = *(const bf16x8*)&lds[1][r * 32 + q8];
        }
#pragma unroll
        for (int ni = 0; ni < 4; ++ni) {
            const int r = wn * 64 + ni * 16 + lm;
            bh[ni] = *(const bf16x8*)&lds[2][r * 32 + q8];
            bl[ni] = *(const bf16x8*)&lds[3][r * 32 + q8];
        }
#pragma unroll
        for (int mi = 0; mi < 4; ++mi)
#pragma unroll
            for (int ni = 0; ni < 4; ++ni) {
                acc[mi][ni] = __builtin_amdgcn_mfma_f32_16x16x32_bf16(ah[mi], bh[ni], acc[mi][ni], 0, 0, 0);
                acc[mi][ni] = __builtin_amdgcn_mfma_f32_16x16x32_bf16(ah[mi], bl[ni], acc[mi][ni], 0, 0, 0);
                acc[mi][ni] = __builtin_amdgcn_mfma_f32_16x16x32_bf16(al[mi], bh[ni], acc[mi][ni], 0, 0, 0);
            }
    }

    // epilogue: C/D layout col = lane&15, row = quad*4 + reg
    const int quad = lane >> 4;
#pragma unroll
    for (int mi = 0; mi < 4; ++mi) {
#pragma unroll
        for (int r = 0; r < 4; ++r) {
            const int gm = by * 128 + wm * 64 + mi * 16 + quad * 4 + r;
            if (gm >= M) continue;
            if (!scatter) {
#pragma unroll
                for (int ni = 0; ni < 4; ++ni) {
                    const int gn = bx * 128 + wn * 64 + ni * 16 + lm;
                    out[(size_t)gm * Ncols + gn] = acc[mi][ni][r] + bias[gn];
                }
            } else {
                const int b   = gm / N_TOK;
                const int tok = gm - b * N_TOK;
#pragma unroll
                for (int ni = 0; ni < 4; ++ni) {
                    const int gn    = bx * 128 + wn * 64 + ni * 16 + lm;
                    const int which = gn >> 10;
                    const int h     = (gn >> 6) & 15;
                    const int d     = gn & 63;
                    const size_t dst = (size_t)which * HEAD_SLAB +
                                       (((size_t)(b * H_ + h)) * N_TOK + tok) * 64 + d;
                    out[dst] = acc[mi][ni][r] + bias[gn];
                }
            }
        }
    }
}

// ---------------------------------------------------------------------------
// In-place RoPE on q/k [B*H, N, D] for tokens n >= PREFIX; folds the score
// scale 1/sqrt(D)=0.125 into q for ALL tokens.
// ---------------------------------------------------------------------------
__global__ __launch_bounds__(256)
void rope_kernel(float* __restrict__ qb, float* __restrict__ kb,
                 const float* __restrict__ sin_, const float* __restrict__ cos_)
{
    const int idx = blockIdx.x * 256 + threadIdx.x;
    const int total = B_ * H_ * N_TOK * 32;
    if (idx >= total) return;
    const int d   = idx & 31;
    const int tmp = idx >> 5;
    const int n   = tmp % N_TOK;
    const int bh  = tmp / N_TOK;

    const size_t base = ((size_t)bh * N_TOK + n) * 64;
    float* q = qb + base;
    const float SCALE = 0.125f;

    if (n < PREFIX) {
        q[d]      *= SCALE;
        q[d + 32] *= SCALE;
        return;
    }
    const int r = n - PREFIX;
    const float c1 = cos_[r * 64 + d];
    const float c2 = cos_[r * 64 + d + 32];
    const float s1 = sin_[r * 64 + d];
    const float s2 = sin_[r * 64 + d + 32];

    const float q1 = q[d], q2 = q[d + 32];
    q[d]      = (q1 * c1 - q2 * s1) * SCALE;
    q[d + 32] = (q2 * c2 + q1 * s2) * SCALE;

    float* k = kb + base;
    const float k1 = k[d], k2 = k[d + 32];
    k[d]      = k1 * c1 - k2 * s1;
    k[d + 32] = k2 * c2 + k1 * s2;
}

// ---------------------------------------------------------------------------
// Flash attention, fp32. One block per (q-tile of 64, bh). 256 threads.
// Epilogue writes bf16 hi/lo split directly (feeds the MFMA proj GEMM).
// Output layout [B, N, H, D] == row-major [M_ROWS, C].
// ---------------------------------------------------------------------------
__global__ __launch_bounds__(256)
void attn_kernel(const float* __restrict__ Qb, const float* __restrict__ Kb,
                 const float* __restrict__ Vb,
                 unsigned short* __restrict__ Ohi, unsigned short* __restrict__ Olo)
{
    __shared__ __align__(16) float Qt[64 * 68];  // [d][q]
    __shared__ __align__(16) float Kt[64 * 68];  // [d][k]
    __shared__ __align__(16) float Vs[64 * 68];  // [k][d]
    __shared__ __align__(16) float Ps[64 * 65];  // [q][k]

    const int tid = threadIdx.x;
    const int tq  = tid >> 4;
    const int tk  = tid & 15;
    const int bh  = blockIdx.y;
    const int q0  = blockIdx.x * 64;

    const float* Q  = Qb + (size_t)bh * N_TOK * 64;
    const float* Kp = Kb + (size_t)bh * N_TOK * 64;
    const float* Vp = Vb + (size_t)bh * N_TOK * 64;

#pragma unroll
    for (int t = 0; t < 4; ++t) {
        const int f   = tid + t * 256;
        const int row = f >> 4;
        const int c4  = (f & 15) << 2;
        const int gq  = q0 + row;
        float4 v = make_float4(0.f, 0.f, 0.f, 0.f);
        if (gq < N_TOK) v = *(const float4*)(Q + (size_t)gq * 64 + c4);
        Qt[(c4 + 0) * 68 + row] = v.x;
        Qt[(c4 + 1) * 68 + row] = v.y;
        Qt[(c4 + 2) * 68 + row] = v.z;
        Qt[(c4 + 3) * 68 + row] = v.w;
    }

    float o[4][4];
    float m_i[4], l_i[4];
#pragma unroll
    for (int i = 0; i < 4; ++i) {
        m_i[i] = -FLT_MAX;
        l_i[i] = 0.f;
#pragma unroll
        for (int j = 0; j < 4; ++j) o[i][j] = 0.f;
    }

    for (int kt = 0; kt < 17; ++kt) {
        const int k0 = kt * 64;
        __syncthreads();
#pragma unroll
        for (int t = 0; t < 4; ++t) {
            const int f   = tid + t * 256;
            const int row = f >> 4;
            const int c4  = (f & 15) << 2;
            const int gk  = k0 + row;
            float4 kv = make_float4(0.f, 0.f, 0.f, 0.f);
            float4 vv = make_float4(0.f, 0.f, 0.f, 0.f);
            if (gk < N_TOK) {
                kv = *(const float4*)(Kp + (size_t)gk * 64 + c4);
                vv = *(const float4*)(Vp + (size_t)gk * 64 + c4);
            }
            Kt[(c4 + 0) * 68 + row] = kv.x;
            Kt[(c4 + 1) * 68 + row] = kv.y;
            Kt[(c4 + 2) * 68 + row] = kv.z;
            Kt[(c4 + 3) * 68 + row] = kv.w;
            *(float4*)&Vs[row * 68 + c4] = vv;
        }
        __syncthreads();

        float s[4][4];
#pragma unroll
        for (int i = 0; i < 4; ++i)
#pragma unroll
            for (int j = 0; j < 4; ++j) s[i][j] = 0.f;

#pragma unroll 8
        for (int d = 0; d < 64; ++d) {
            const float4 q4 = *(const float4*)&Qt[d * 68 + 4 * tq];
            const float4 k4 = *(const float4*)&Kt[d * 68 + 4 * tk];
            const float qa[4] = {q4.x, q4.y, q4.z, q4.w};
            const float ka[4] = {k4.x, k4.y, k4.z, k4.w};
#pragma unroll
            for (int i = 0; i < 4; ++i)
#pragma unroll
                for (int j = 0; j < 4; ++j)
                    s[i][j] = fmaf(qa[i], ka[j], s[i][j]);
        }

        if (k0 + 64 > N_TOK) {
#pragma unroll
            for (int j = 0; j < 4; ++j) {
                if (k0 + 4 * tk + j >= N_TOK) {
#pragma unroll
                    for (int i = 0; i < 4; ++i) s[i][j] = -FLT_MAX;
                }
            }
        }

#pragma unroll
        for (int i = 0; i < 4; ++i) {
            float mt = fmaxf(fmaxf(s[i][0], s[i][1]), fmaxf(s[i][2], s[i][3]));
            mt = fmaxf(mt, __shfl_xor(mt, 1));
            mt = fmaxf(mt, __shfl_xor(mt, 2));
            mt = fmaxf(mt, __shfl_xor(mt, 4));
            mt = fmaxf(mt, __shfl_xor(mt, 8));
            const float mnew  = fmaxf(m_i[i], mt);
            const float alpha = expf(m_i[i] - mnew);
            float rs = 0.f;
#pragma unroll
            for (int j = 0; j < 4; ++j) {
                const float p = expf(s[i][j] - mnew);
                s[i][j] = p;
                rs += p;
            }
            rs += __shfl_xor(rs, 1);
            rs += __shfl_xor(rs, 2);
            rs += __shfl_xor(rs, 4);
            rs += __shfl_xor(rs, 8);
            l_i[i] = l_i[i] * alpha + rs;
            m_i[i] = mnew;
#pragma unroll
            for (int j = 0; j < 4; ++j) o[i][j] *= alpha;
        }

#pragma unroll
        for (int i = 0; i < 4; ++i)
#pragma unroll
            for (int j = 0; j < 4; ++j)
                Ps[(4 * tq + i) * 65 + 4 * tk + j] = s[i][j];
        __syncthreads();

#pragma unroll 8
        for (int key = 0; key < 64; ++key) {
            const float4 v4 = *(const float4*)&Vs[key * 68 + 4 * tk];
            const float va[4] = {v4.x, v4.y, v4.z, v4.w};
            const float p0 = Ps[(4 * tq + 0) * 65 + key];
            const float p1 = Ps[(4 * tq + 1) * 65 + key];
            const float p2 = Ps[(4 * tq + 2) * 65 + key];
            const float p3 = Ps[(4 * tq + 3) * 65 + key];
#pragma unroll
            for (int j = 0; j < 4; ++j) {
                o[0][j] = fmaf(p0, va[j], o[0][j]);
                o[1][j] = fmaf(p1, va[j], o[1][j]);
                o[2][j] = fmaf(p2, va[j], o[2][j]);
                o[3][j] = fmaf(p3, va[j], o[3][j]);
            }
        }
    }

    const int b = bh >> 4;
    const int h = bh & 15;
#pragma unroll
    for (int i = 0; i < 4; ++i) {
        const int gq = q0 + 4 * tq + i;
        if (gq < N_TOK) {
            const float inv = 1.0f / l_i[i];
            const size_t base = (((size_t)(b * N_TOK + gq)) * H_ + h) * D_ + 4 * tk;
            ushort4 hv, lv;
            float v0 = o[i][0] * inv, v1 = o[i][1] * inv,
                  v2 = o[i][2] * inv, v3 = o[i][3] * inv;
            hv.x = f2bf(v0); lv.x = f2bf(v0 - bf2f(hv.x));
            hv.y = f2bf(v1); lv.y = f2bf(v1 - bf2f(hv.y));
            hv.z = f2bf(v2); lv.z = f2bf(v2 - bf2f(hv.z));
            hv.w = f2bf(v3); lv.w = f2bf(v3 - bf2f(hv.w));
            *(ushort4*)(Ohi + base) = hv;
            *(ushort4*)(Olo + base) = lv;
        }
    }
}

// ---------------------------------------------------------------------------
// Workspace budget note: round 1 PASSED with exactly 4 fp32 slabs
// (269,746,176 B); round 2 added +16.8 MB of split buffers and aborted with a
// GPU memory fault. This version keeps ws at EXACTLY 4 slabs and parks the
// split buffers in dead memory:
//   - x_hi/x_lo     -> slab 4 (reused as attn_hi/attn_lo after GEMM1)
//   - wq_hi/wq_lo   -> d_out (unused until GEMM2, which fully overwrites it)
//   - wp_hi/wp_lo   -> q_buf (q is dead after attention; split launched then)
// ---------------------------------------------------------------------------
extern "C" void kernel_launch(void* const* d_in, const int* in_sizes, int n_in,
                              void* d_out, int out_size, void* d_ws, size_t ws_size,
                              hipStream_t stream)
{
    const float* x        = (const float*)d_in[0];
    const float* rope_sin = (const float*)d_in[1];
    const float* rope_cos = (const float*)d_in[2];
    const float* W_qkv    = (const float*)d_in[3];
    const float* b_qkv    = (const float*)d_in[4];
    const float* W_proj   = (const float*)d_in[5];
    const float* b_proj   = (const float*)d_in[6];
    float* out = (float*)d_out;

    float* q_buf = (float*)d_ws;
    float* k_buf = q_buf + HEAD_SLAB;
    float* v_buf = q_buf + 2 * HEAD_SLAB;
    float* slab4 = q_buf + 3 * HEAD_SLAB;   // 67.4 MB scratch slab

    unsigned short* x_hi = (unsigned short*)slab4;
    unsigned short* x_lo = x_hi + (size_t)M_ROWS * C_;
    unsigned short* attn_hi = x_hi;          // x splits dead after GEMM1
    unsigned short* attn_lo = x_lo;
    unsigned short* wq_hi = (unsigned short*)d_out;          // d_out as scratch
    unsigned short* wq_lo = wq_hi + (size_t)3 * C_ * C_;     // 12.6 MB <= 67.4 MB
    unsigned short* wp_hi = (unsigned short*)q_buf;          // q dead after attn
    unsigned short* wp_lo = wp_hi + (size_t)C_ * C_;

    // 0) fp32 -> bf16 hi/lo splits for x and W_qkv
    {
        const int n4x = M_ROWS * C_ / 4;
        split_kernel<<<(n4x + 255) / 256, 256, 0, stream>>>(x, x_hi, x_lo, n4x);
        const int n4q = 3 * C_ * C_ / 4;
        split_kernel<<<(n4q + 255) / 256, 256, 0, stream>>>(W_qkv, wq_hi, wq_lo, n4q);
    }
    // 1) QKV projection (MFMA), scattered into q/k/v [B,H,N,D]
    {
        dim3 grid(3 * C_ / 128, (M_ROWS + 127) / 128);
        gemm_mfma<<<grid, 256, 0, stream>>>(x_hi, x_lo, wq_hi, wq_lo, b_qkv,
                                            q_buf, M_ROWS, 3 * C_, C_, 1);
    }
    // 2) RoPE in-place on q/k (+ fold 1/sqrt(D) into q)
    {
        const int total = B_ * H_ * N_TOK * 32;
        rope_kernel<<<(total + 255) / 256, 256, 0, stream>>>(q_buf, k_buf,
                                                             rope_sin, rope_cos);
    }
    // 3) Flash attention -> attn hi/lo bf16 [B, N, H, D] (overwrites x splits)
    {
        dim3 grid((N_TOK + 63) / 64, B_ * H_);
        attn_kernel<<<grid, 256, 0, stream>>>(q_buf, k_buf, v_buf, attn_hi, attn_lo);
    }
    // 3b) split W_proj into the now-dead q slab
    {
        const int n4p = C_ * C_ / 4;
        split_kernel<<<(n4p + 255) / 256, 256, 0, stream>>>(W_proj, wp_hi, wp_lo, n4p);
    }
    // 4) Output projection (MFMA) -> d_out (overwrites wq splits)
    {
        dim3 grid(C_ / 128, (M_ROWS + 127) / 128);
        gemm_mfma<<<grid, 256, 0, stream>>>(attn_hi, attn_lo, wp_hi, wp_lo, b_proj,
                                            out, M_ROWS, C_, C_, 0);
    }
}

// Round 4
// 1741.941 us; speedup vs baseline: 2.2248x; 1.1473x over previous
//
#include <hip/hip_runtime.h>
#include <cfloat>
#include <math.h>

#define B_      16
#define N_TOK   1029
#define C_      1024
#define H_      16
#define D_      64
#define PREFIX  5
#define M_ROWS  (B_ * N_TOK)                       // 16464
#define HEAD_SLAB ((size_t)B_ * H_ * N_TOK * D_)   // 16,859,136 floats per q/k/v buffer

typedef __attribute__((ext_vector_type(8))) short bf16x8;
typedef __attribute__((ext_vector_type(4))) float f32x4;

// ---- bf16 helpers (RNE), raw ushort storage ------------------------------
__device__ __forceinline__ unsigned short f2bf(float f) {
    unsigned u = __float_as_uint(f);
    u += 0x7fffu + ((u >> 16) & 1u);          // round-to-nearest-even
    return (unsigned short)(u >> 16);
}
__device__ __forceinline__ float bf2f(unsigned short h) {
    return __uint_as_float(((unsigned)h) << 16);
}

// ---------------------------------------------------------------------------
// Split fp32 array into bf16 hi + bf16 lo (residual). n4 = count/4.
// ---------------------------------------------------------------------------
__global__ __launch_bounds__(256)
void split_kernel(const float* __restrict__ in, unsigned short* __restrict__ hi,
                  unsigned short* __restrict__ lo, int n4)
{
    const int i = blockIdx.x * 256 + threadIdx.x;
    if (i >= n4) return;
    const float4 v = ((const float4*)in)[i];
    ushort4 h, l;
    h.x = f2bf(v.x); l.x = f2bf(v.x - bf2f(h.x));
    h.y = f2bf(v.y); l.y = f2bf(v.y - bf2f(h.y));
    h.z = f2bf(v.z); l.z = f2bf(v.z - bf2f(h.z));
    h.w = f2bf(v.w); l.w = f2bf(v.w - bf2f(h.w));
    ((ushort4*)hi)[i] = h;
    ((ushort4*)lo)[i] = l;
}

// ---------------------------------------------------------------------------
// MFMA GEMM: out = (Ahi+Alo) @ (Whi+Wlo)^T + bias, dropping lo*lo.
// (unchanged from round 3 — passed at absmax 9.8e-4)
// ---------------------------------------------------------------------------
__global__ __launch_bounds__(256)
void gemm_mfma(const unsigned short* __restrict__ Ahi, const unsigned short* __restrict__ Alo,
               const unsigned short* __restrict__ Whi, const unsigned short* __restrict__ Wlo,
               const float* __restrict__ bias, float* __restrict__ out,
               int M, int Ncols, int K, int scatter)
{
    __shared__ unsigned short lds[4][128 * 32];   // Ahi | Alo | Whi | Wlo tiles, 8KB each

    const int tid  = threadIdx.x;
    const int wave = tid >> 6;
    const int lane = tid & 63;
    const int bx = blockIdx.x, by = blockIdx.y;
    const int wm = wave >> 1, wn = wave & 1;

    f32x4 acc[4][4];
#pragma unroll
    for (int mi = 0; mi < 4; ++mi)
#pragma unroll
        for (int ni = 0; ni < 4; ++ni)
            acc[mi][ni] = (f32x4){0.f, 0.f, 0.f, 0.f};

    const unsigned short* src = (wave == 0) ? Ahi : (wave == 1) ? Alo
                              : (wave == 2) ? Whi : Wlo;
    const bool isA  = (wave < 2);
    const int  row0 = isA ? by * 128 : bx * 128;
    const int  rlo  = lane >> 2;
    const int  koff = (lane & 3) << 3;

    const int lm = lane & 15;
    const int q8 = (lane >> 4) << 3;

    for (int k0 = 0; k0 < K; k0 += 32) {
        __syncthreads();
#pragma unroll
        for (int i = 0; i < 8; ++i) {
            int grow = row0 + i * 16 + rlo;
            if (isA && grow > M - 1) grow = M - 1;
            const unsigned short* g = src + (size_t)grow * K + k0 + koff;
            __builtin_amdgcn_global_load_lds(
                (__attribute__((address_space(1))) void*)g,
                (__attribute__((address_space(3))) void*)&lds[wave][i * 512],
                16, 0, 0);
        }
        __syncthreads();

        bf16x8 ah[4], al[4], bh[4], bl[4];
#pragma unroll
        for (int mi = 0; mi < 4; ++mi) {
            const int r = wm * 64 + mi * 16 + lm;
            ah[mi] = *(const bf16x8*)&lds[0][r * 32 + q8];
            al[mi] = *(const bf16x8*)&lds[1][r * 32 + q8];
        }
#pragma unroll
        for (int ni = 0; ni < 4; ++ni) {
            const int r = wn * 64 + ni * 16 + lm;
            bh[ni] = *(const bf16x8*)&lds[2][r * 32 + q8];
            bl[ni] = *(const bf16x8*)&lds[3][r * 32 + q8];
        }
#pragma unroll
        for (int mi = 0; mi < 4; ++mi)
#pragma unroll
            for (int ni = 0; ni < 4; ++ni) {
                acc[mi][ni] = __builtin_amdgcn_mfma_f32_16x16x32_bf16(ah[mi], bh[ni], acc[mi][ni], 0, 0, 0);
                acc[mi][ni] = __builtin_amdgcn_mfma_f32_16x16x32_bf16(ah[mi], bl[ni], acc[mi][ni], 0, 0, 0);
                acc[mi][ni] = __builtin_amdgcn_mfma_f32_16x16x32_bf16(al[mi], bh[ni], acc[mi][ni], 0, 0, 0);
            }
    }

    const int quad = lane >> 4;
#pragma unroll
    for (int mi = 0; mi < 4; ++mi) {
#pragma unroll
        for (int r = 0; r < 4; ++r) {
            const int gm = by * 128 + wm * 64 + mi * 16 + quad * 4 + r;
            if (gm >= M) continue;
            if (!scatter) {
#pragma unroll
                for (int ni = 0; ni < 4; ++ni) {
                    const int gn = bx * 128 + wn * 64 + ni * 16 + lm;
                    out[(size_t)gm * Ncols + gn] = acc[mi][ni][r] + bias[gn];
                }
            } else {
                const int b   = gm / N_TOK;
                const int tok = gm - b * N_TOK;
#pragma unroll
                for (int ni = 0; ni < 4; ++ni) {
                    const int gn    = bx * 128 + wn * 64 + ni * 16 + lm;
                    const int which = gn >> 10;
                    const int h     = (gn >> 6) & 15;
                    const int d     = gn & 63;
                    const size_t dst = (size_t)which * HEAD_SLAB +
                                       (((size_t)(b * H_ + h)) * N_TOK + tok) * 64 + d;
                    out[dst] = acc[mi][ni][r] + bias[gn];
                }
            }
        }
    }
}

// ---------------------------------------------------------------------------
// In-place RoPE on q/k (+ fold 1/sqrt(D)=0.125 into q). Unchanged.
// ---------------------------------------------------------------------------
__global__ __launch_bounds__(256)
void rope_kernel(float* __restrict__ qb, float* __restrict__ kb,
                 const float* __restrict__ sin_, const float* __restrict__ cos_)
{
    const int idx = blockIdx.x * 256 + threadIdx.x;
    const int total = B_ * H_ * N_TOK * 32;
    if (idx >= total) return;
    const int d   = idx & 31;
    const int tmp = idx >> 5;
    const int n   = tmp % N_TOK;
    const int bh  = tmp / N_TOK;

    const size_t base = ((size_t)bh * N_TOK + n) * 64;
    float* q = qb + base;
    const float SCALE = 0.125f;

    if (n < PREFIX) {
        q[d]      *= SCALE;
        q[d + 32] *= SCALE;
        return;
    }
    const int r = n - PREFIX;
    const float c1 = cos_[r * 64 + d];
    const float c2 = cos_[r * 64 + d + 32];
    const float s1 = sin_[r * 64 + d];
    const float s2 = sin_[r * 64 + d + 32];

    const float q1 = q[d], q2 = q[d + 32];
    q[d]      = (q1 * c1 - q2 * s1) * SCALE;
    q[d + 32] = (q2 * c2 + q1 * s2) * SCALE;

    float* k = kb + base;
    const float k1 = k[d], k2 = k[d + 32];
    k[d]      = k1 * c1 - k2 * s1;
    k[d + 32] = k2 * c2 + k1 * s2;
}

// ---------------------------------------------------------------------------
// MFMA flash attention. One block per (128-q-tile, bh); 4 waves, each owning
// 32 q-rows. Q fragments (bf16 hi/lo) in REGISTERS (no LDS). Per 64-key tile:
//   K staged [key][d] bf16 hi/lo, V staged transposed [d][key] bf16 hi/lo,
//   both with XOR-chunk swizzle (chunk ^= row&7) so B-frag ds_read_b128 are
//   16B-aligned and bank-spread with zero padding (LDS = 48KB -> 3 blocks/CU).
// QK^T: 3 MFMAs (hi*hi+hi*lo+lo*hi) -> scores ~exact. Online softmax in
// C-layout regs (quad-local shuffle reductions, __expf). P (bf16 hi only)
// round-trips through wave-private swizzled LDS (C-layout -> A-layout).
// PV: 2 MFMAs (P*Vhi + P*Vlo). Output -> bf16 hi/lo split, [B,N,H,D].
// ---------------------------------------------------------------------------
__global__ __launch_bounds__(256, 3)
void attn_mfma(const float* __restrict__ Qb, const float* __restrict__ Kb,
               const float* __restrict__ Vb,
               unsigned short* __restrict__ Ohi, unsigned short* __restrict__ Olo)
{
    __shared__ unsigned short Khi[64 * 64], Klo[64 * 64];    // [key][d] swizzled
    __shared__ unsigned short Vthi[64 * 64], Vtlo[64 * 64];  // [d][key] swizzled
    __shared__ unsigned short Pl[128 * 64];                  // [q][key] swizzled

    const int tid  = threadIdx.x;
    const int wave = tid >> 6;
    const int lane = tid & 63;
    const int lm   = lane & 15;
    const int quad = lane >> 4;
    const int q8   = quad * 8;
    const int bh   = blockIdx.y;
    const int q0   = blockIdx.x * 128;
    const int b    = bh >> 4;
    const int h    = bh & 15;

    const float* Qp = Qb + (size_t)bh * N_TOK * 64;
    const float* Kp = Kb + (size_t)bh * N_TOK * 64;
    const float* Vp = Vb + (size_t)bh * N_TOK * 64;

    // ---- Q fragments in registers: A-layout, rows wave*32 + rt*16 + lm ----
    bf16x8 qh[2][2], ql[2][2];
#pragma unroll
    for (int rt = 0; rt < 2; ++rt) {
        int row = q0 + wave * 32 + rt * 16 + lm;
        if (row > N_TOK - 1) row = N_TOK - 1;   // clamp; masked rows never stored
#pragma unroll
        for (int s = 0; s < 2; ++s) {
            const float* p = Qp + (size_t)row * 64 + s * 32 + q8;
            const float4 a = *(const float4*)p;
            const float4 c = *(const float4*)(p + 4);
            const float vals[8] = {a.x, a.y, a.z, a.w, c.x, c.y, c.z, c.w};
            bf16x8 hi, lo;
#pragma unroll
            for (int j = 0; j < 8; ++j) {
                const unsigned short hb = f2bf(vals[j]);
                hi[j] = (short)hb;
                lo[j] = (short)f2bf(vals[j] - bf2f(hb));
            }
            qh[rt][s] = hi;
            ql[rt][s] = lo;
        }
    }

    f32x4 o[2][4];
    float m_i[2][4], l_i[2][4];
#pragma unroll
    for (int rt = 0; rt < 2; ++rt)
#pragma unroll
        for (int r = 0; r < 4; ++r) {
            m_i[rt][r] = -FLT_MAX;
            l_i[rt][r] = 0.f;
            o[rt][r] = (f32x4){0.f, 0.f, 0.f, 0.f};
        }

    for (int kt = 0; kt < 17; ++kt) {
        const int kt0 = kt * 64;
        __syncthreads();   // prev iteration's frag reads done before restaging

        // ---- stage K: [key][d], c4-fast mapping (coalesced global reads) ----
#pragma unroll
        for (int p4 = 0; p4 < 4; ++p4) {
            const int e   = p4 * 256 + tid;       // 0..1023 float4s
            const int key = e >> 4;               // 0..63
            const int c4  = (e & 15) << 2;        // 0..60
            int gk = kt0 + key;
            if (gk > N_TOK - 1) gk = N_TOK - 1;   // clamp; masked via -FLT_MAX
            const float4 kv = *(const float4*)(Kp + (size_t)gk * 64 + c4);
            ushort4 hh, ll;
            hh.x = f2bf(kv.x); ll.x = f2bf(kv.x - bf2f(hh.x));
            hh.y = f2bf(kv.y); ll.y = f2bf(kv.y - bf2f(hh.y));
            hh.z = f2bf(kv.z); ll.z = f2bf(kv.z - bf2f(hh.z));
            hh.w = f2bf(kv.w); ll.w = f2bf(kv.w - bf2f(hh.w));
            const int idx = key * 64 + ((((c4 >> 3) ^ (key & 7)) << 3) | (c4 & 7));
            *(ushort4*)&Khi[idx] = hh;
            *(ushort4*)&Klo[idx] = ll;
        }
        // ---- stage V transposed: [d][key], key-fast mapping ----
#pragma unroll
        for (int p4 = 0; p4 < 4; ++p4) {
            const int e   = p4 * 256 + tid;
            const int key = e & 63;
            const int c4  = (e >> 6) << 2;        // 0..60  (d base)
            int gk = kt0 + key;
            if (gk > N_TOK - 1) gk = N_TOK - 1;   // garbage * P=0 -> harmless
            const float4 vv = *(const float4*)(Vp + (size_t)gk * 64 + c4);
            const float va[4] = {vv.x, vv.y, vv.z, vv.w};
#pragma unroll
            for (int i = 0; i < 4; ++i) {
                const int row = c4 + i;           // d index
                const unsigned short hb = f2bf(va[i]);
                const int idx = row * 64 + ((((key >> 3) ^ (row & 7)) << 3) | (key & 7));
                Vthi[idx] = hb;
                Vtlo[idx] = f2bf(va[i] - bf2f(hb));
            }
        }
        __syncthreads();

        // ---- QK^T: S[32 q][64 key] per wave ----
        f32x4 s_acc[2][4];
#pragma unroll
        for (int rt = 0; rt < 2; ++rt)
#pragma unroll
            for (int ct = 0; ct < 4; ++ct)
                s_acc[rt][ct] = (f32x4){0.f, 0.f, 0.f, 0.f};

#pragma unroll
        for (int ct = 0; ct < 4; ++ct) {
            const int krow = ct * 16 + lm;        // key index (B-operand n)
#pragma unroll
            for (int s = 0; s < 2; ++s) {
                const int chunk = ((s * 4 + quad) ^ (krow & 7)) << 3;
                const bf16x8 kbh = *(const bf16x8*)&Khi[krow * 64 + chunk];
                const bf16x8 kbl = *(const bf16x8*)&Klo[krow * 64 + chunk];
#pragma unroll
                for (int rt = 0; rt < 2; ++rt) {
                    s_acc[rt][ct] = __builtin_amdgcn_mfma_f32_16x16x32_bf16(qh[rt][s], kbh, s_acc[rt][ct], 0, 0, 0);
                    s_acc[rt][ct] = __builtin_amdgcn_mfma_f32_16x16x32_bf16(qh[rt][s], kbl, s_acc[rt][ct], 0, 0, 0);
                    s_acc[rt][ct] = __builtin_amdgcn_mfma_f32_16x16x32_bf16(ql[rt][s], kbh, s_acc[rt][ct], 0, 0, 0);
                }
            }
        }

        // ---- mask OOB keys (last tile only) ----
        if (kt0 + 64 > N_TOK) {
#pragma unroll
            for (int ct = 0; ct < 4; ++ct) {
                if (kt0 + ct * 16 + lm >= N_TOK) {
#pragma unroll
                    for (int rt = 0; rt < 2; ++rt)
#pragma unroll
                        for (int r = 0; r < 4; ++r) s_acc[rt][ct][r] = -FLT_MAX;
                }
            }
        }

        // ---- online softmax (per q-row; C-layout row = quad*4+r) ----
#pragma unroll
        for (int rt = 0; rt < 2; ++rt) {
#pragma unroll
            for (int r = 0; r < 4; ++r) {
                float mt = fmaxf(fmaxf(s_acc[rt][0][r], s_acc[rt][1][r]),
                                 fmaxf(s_acc[rt][2][r], s_acc[rt][3][r]));
                mt = fmaxf(mt, __shfl_xor(mt, 1));
                mt = fmaxf(mt, __shfl_xor(mt, 2));
                mt = fmaxf(mt, __shfl_xor(mt, 4));
                mt = fmaxf(mt, __shfl_xor(mt, 8));
                const float mnew  = fmaxf(m_i[rt][r], mt);
                const float alpha = __expf(m_i[rt][r] - mnew);
                float pv[4], rs = 0.f;
#pragma unroll
                for (int ct = 0; ct < 4; ++ct) {
                    pv[ct] = __expf(s_acc[rt][ct][r] - mnew);
                    rs += pv[ct];
                }
                rs += __shfl_xor(rs, 1);
                rs += __shfl_xor(rs, 2);
                rs += __shfl_xor(rs, 4);
                rs += __shfl_xor(rs, 8);
                l_i[rt][r] = l_i[rt][r] * alpha + rs;
                m_i[rt][r] = mnew;
#pragma unroll
                for (int dt = 0; dt < 4; ++dt) o[rt][dt][r] *= alpha;
                // publish P (bf16 hi) to wave-private swizzled LDS
                const int prow = wave * 32 + rt * 16 + quad * 4 + r;
#pragma unroll
                for (int ct = 0; ct < 4; ++ct) {
                    const int col = ct * 16 + lm;
                    const int idx = prow * 64 + ((((col >> 3) ^ (prow & 7)) << 3) | (col & 7));
                    Pl[idx] = f2bf(pv[ct]);
                }
            }
        }

        // ---- PV: o[32 q][64 d] += P @ V  (wave-private P: no barrier) ----
#pragma unroll
        for (int ks = 0; ks < 2; ++ks) {
            bf16x8 pf[2];
#pragma unroll
            for (int rt = 0; rt < 2; ++rt) {
                const int prow = wave * 32 + rt * 16 + lm;
                const int chunk = ((ks * 4 + quad) ^ (prow & 7)) << 3;
                pf[rt] = *(const bf16x8*)&Pl[prow * 64 + chunk];
            }
#pragma unroll
            for (int dt = 0; dt < 4; ++dt) {
                const int vrow = dt * 16 + lm;    // d index (B-operand n)
                const int chunk = ((ks * 4 + quad) ^ (vrow & 7)) << 3;
                const bf16x8 vh = *(const bf16x8*)&Vthi[vrow * 64 + chunk];
                const bf16x8 vl = *(const bf16x8*)&Vtlo[vrow * 64 + chunk];
#pragma unroll
                for (int rt = 0; rt < 2; ++rt) {
                    o[rt][dt] = __builtin_amdgcn_mfma_f32_16x16x32_bf16(pf[rt], vh, o[rt][dt], 0, 0, 0);
                    o[rt][dt] = __builtin_amdgcn_mfma_f32_16x16x32_bf16(pf[rt], vl, o[rt][dt], 0, 0, 0);
                }
            }
        }
    }

    // ---- epilogue: normalize, bf16 hi/lo split, store [B,N,H,D] ----
#pragma unroll
    for (int rt = 0; rt < 2; ++rt) {
#pragma unroll
        for (int r = 0; r < 4; ++r) {
            const int gq = q0 + wave * 32 + rt * 16 + quad * 4 + r;
            if (gq >= N_TOK) continue;
            const float inv = 1.0f / l_i[rt][r];
            const size_t base = (((size_t)(b * N_TOK + gq)) * H_ + h) * D_;
#pragma unroll
            for (int dt = 0; dt < 4; ++dt) {
                const float val = o[rt][dt][r] * inv;
                const unsigned short hb = f2bf(val);
                Ohi[base + dt * 16 + lm] = hb;
                Olo[base + dt * 16 + lm] = f2bf(val - bf2f(hb));
            }
        }
    }
}

// ---------------------------------------------------------------------------
// ws = EXACTLY 4 fp32 slabs (269,746,176 B — proven budget). Split buffers
// live in dead memory: x splits -> slab4 (reused as attn splits), wq splits
// -> d_out (dead until GEMM2), wp splits -> q_buf (dead after attention).
// ---------------------------------------------------------------------------
extern "C" void kernel_launch(void* const* d_in, const int* in_sizes, int n_in,
                              void* d_out, int out_size, void* d_ws, size_t ws_size,
                              hipStream_t stream)
{
    const float* x        = (const float*)d_in[0];
    const float* rope_sin = (const float*)d_in[1];
    const float* rope_cos = (const float*)d_in[2];
    const float* W_qkv    = (const float*)d_in[3];
    const float* b_qkv    = (const float*)d_in[4];
    const float* W_proj   = (const float*)d_in[5];
    const float* b_proj   = (const float*)d_in[6];
    float* out = (float*)d_out;

    float* q_buf = (float*)d_ws;
    float* k_buf = q_buf + HEAD_SLAB;
    float* v_buf = q_buf + 2 * HEAD_SLAB;
    float* slab4 = q_buf + 3 * HEAD_SLAB;

    unsigned short* x_hi = (unsigned short*)slab4;
    unsigned short* x_lo = x_hi + (size_t)M_ROWS * C_;
    unsigned short* attn_hi = x_hi;
    unsigned short* attn_lo = x_lo;
    unsigned short* wq_hi = (unsigned short*)d_out;
    unsigned short* wq_lo = wq_hi + (size_t)3 * C_ * C_;
    unsigned short* wp_hi = (unsigned short*)q_buf;
    unsigned short* wp_lo = wp_hi + (size_t)C_ * C_;

    // 0) fp32 -> bf16 hi/lo splits for x and W_qkv
    {
        const int n4x = M_ROWS * C_ / 4;
        split_kernel<<<(n4x + 255) / 256, 256, 0, stream>>>(x, x_hi, x_lo, n4x);
        const int n4q = 3 * C_ * C_ / 4;
        split_kernel<<<(n4q + 255) / 256, 256, 0, stream>>>(W_qkv, wq_hi, wq_lo, n4q);
    }
    // 1) QKV projection (MFMA), scattered into q/k/v [B,H,N,D]
    {
        dim3 grid(3 * C_ / 128, (M_ROWS + 127) / 128);
        gemm_mfma<<<grid, 256, 0, stream>>>(x_hi, x_lo, wq_hi, wq_lo, b_qkv,
                                            q_buf, M_ROWS, 3 * C_, C_, 1);
    }
    // 2) RoPE in-place on q/k (+ fold 1/sqrt(D) into q)
    {
        const int total = B_ * H_ * N_TOK * 32;
        rope_kernel<<<(total + 255) / 256, 256, 0, stream>>>(q_buf, k_buf,
                                                             rope_sin, rope_cos);
    }
    // 3) MFMA flash attention -> attn hi/lo bf16 [B, N, H, D]
    {
        dim3 grid((N_TOK + 127) / 128, B_ * H_);
        attn_mfma<<<grid, 256, 0, stream>>>(q_buf, k_buf, v_buf, attn_hi, attn_lo);
    }
    // 3b) split W_proj into the now-dead q slab
    {
        const int n4p = C_ * C_ / 4;
        split_kernel<<<(n4p + 255) / 256, 256, 0, stream>>>(W_proj, wp_hi, wp_lo, n4p);
    }
    // 4) Output projection (MFMA) -> d_out (overwrites wq splits)
    {
        dim3 grid(C_ / 128, (M_ROWS + 127) / 128);
        gemm_mfma<<<grid, 256, 0, stream>>>(attn_hi, attn_lo, wp_hi, wp_lo, b_proj,
                                            out, M_ROWS, C_, C_, 0);
    }
}

// Round 5
// 1551.950 us; speedup vs baseline: 2.4972x; 1.1224x over previous
//
#include <hip/hip_runtime.h>
#include <cfloat>
#include <math.h>

#define B_      16
#define N_TOK   1029
#define C_      1024
#define H_      16
#define D_      64
#define PREFIX  5
#define M_ROWS  (B_ * N_TOK)                       // 16464
#define HEAD_SLAB ((size_t)B_ * H_ * N_TOK * D_)   // 16,859,136 floats (= M_ROWS*C_)
#define VT_STRIDE 1088                             // 17*64: padded key dim for V^T slab

typedef __attribute__((ext_vector_type(8))) short bf16x8;
typedef __attribute__((ext_vector_type(4))) float f32x4;

// ---- bf16 helpers (RNE), raw ushort storage ------------------------------
__device__ __forceinline__ unsigned short f2bf(float f) {
    unsigned u = __float_as_uint(f);
    u += 0x7fffu + ((u >> 16) & 1u);          // round-to-nearest-even
    return (unsigned short)(u >> 16);
}
__device__ __forceinline__ float bf2f(unsigned short h) {
    return __uint_as_float(((unsigned)h) << 16);
}

// ---------------------------------------------------------------------------
// Split fp32 array into bf16 hi + bf16 lo (residual). n4 = count/4.
// ---------------------------------------------------------------------------
__global__ __launch_bounds__(256)
void split_kernel(const float* __restrict__ in, unsigned short* __restrict__ hi,
                  unsigned short* __restrict__ lo, int n4)
{
    const int i = blockIdx.x * 256 + threadIdx.x;
    if (i >= n4) return;
    const float4 v = ((const float4*)in)[i];
    ushort4 h, l;
    h.x = f2bf(v.x); l.x = f2bf(v.x - bf2f(h.x));
    h.y = f2bf(v.y); l.y = f2bf(v.y - bf2f(h.y));
    h.z = f2bf(v.z); l.z = f2bf(v.z - bf2f(h.z));
    h.w = f2bf(v.w); l.w = f2bf(v.w - bf2f(h.w));
    ((ushort4*)hi)[i] = h;
    ((ushort4*)lo)[i] = l;
}

// ---------------------------------------------------------------------------
// MFMA GEMM (unchanged from round 3 — passed at absmax 9.8e-4).
// ---------------------------------------------------------------------------
__global__ __launch_bounds__(256)
void gemm_mfma(const unsigned short* __restrict__ Ahi, const unsigned short* __restrict__ Alo,
               const unsigned short* __restrict__ Whi, const unsigned short* __restrict__ Wlo,
               const float* __restrict__ bias, float* __restrict__ out,
               int M, int Ncols, int K, int scatter)
{
    __shared__ unsigned short lds[4][128 * 32];

    const int tid  = threadIdx.x;
    const int wave = tid >> 6;
    const int lane = tid & 63;
    const int bx = blockIdx.x, by = blockIdx.y;
    const int wm = wave >> 1, wn = wave & 1;

    f32x4 acc[4][4];
#pragma unroll
    for (int mi = 0; mi < 4; ++mi)
#pragma unroll
        for (int ni = 0; ni < 4; ++ni)
            acc[mi][ni] = (f32x4){0.f, 0.f, 0.f, 0.f};

    const unsigned short* src = (wave == 0) ? Ahi : (wave == 1) ? Alo
                              : (wave == 2) ? Whi : Wlo;
    const bool isA  = (wave < 2);
    const int  row0 = isA ? by * 128 : bx * 128;
    const int  rlo  = lane >> 2;
    const int  koff = (lane & 3) << 3;

    const int lm = lane & 15;
    const int q8 = (lane >> 4) << 3;

    for (int k0 = 0; k0 < K; k0 += 32) {
        __syncthreads();
#pragma unroll
        for (int i = 0; i < 8; ++i) {
            int grow = row0 + i * 16 + rlo;
            if (isA && grow > M - 1) grow = M - 1;
            const unsigned short* g = src + (size_t)grow * K + k0 + koff;
            __builtin_amdgcn_global_load_lds(
                (__attribute__((address_space(1))) void*)g,
                (__attribute__((address_space(3))) void*)&lds[wave][i * 512],
                16, 0, 0);
        }
        __syncthreads();

        bf16x8 ah[4], al[4], bh[4], bl[4];
#pragma unroll
        for (int mi = 0; mi < 4; ++mi) {
            const int r = wm * 64 + mi * 16 + lm;
            ah[mi] = *(const bf16x8*)&lds[0][r * 32 + q8];
            al[mi] = *(const bf16x8*)&lds[1][r * 32 + q8];
        }
#pragma unroll
        for (int ni = 0; ni < 4; ++ni) {
            const int r = wn * 64 + ni * 16 + lm;
            bh[ni] = *(const bf16x8*)&lds[2][r * 32 + q8];
            bl[ni] = *(const bf16x8*)&lds[3][r * 32 + q8];
        }
#pragma unroll
        for (int mi = 0; mi < 4; ++mi)
#pragma unroll
            for (int ni = 0; ni < 4; ++ni) {
                acc[mi][ni] = __builtin_amdgcn_mfma_f32_16x16x32_bf16(ah[mi], bh[ni], acc[mi][ni], 0, 0, 0);
                acc[mi][ni] = __builtin_amdgcn_mfma_f32_16x16x32_bf16(ah[mi], bl[ni], acc[mi][ni], 0, 0, 0);
                acc[mi][ni] = __builtin_amdgcn_mfma_f32_16x16x32_bf16(al[mi], bh[ni], acc[mi][ni], 0, 0, 0);
            }
    }

    const int quad = lane >> 4;
#pragma unroll
    for (int mi = 0; mi < 4; ++mi) {
#pragma unroll
        for (int r = 0; r < 4; ++r) {
            const int gm = by * 128 + wm * 64 + mi * 16 + quad * 4 + r;
            if (gm >= M) continue;
            if (!scatter) {
#pragma unroll
                for (int ni = 0; ni < 4; ++ni) {
                    const int gn = bx * 128 + wn * 64 + ni * 16 + lm;
                    out[(size_t)gm * Ncols + gn] = acc[mi][ni][r] + bias[gn];
                }
            } else {
                const int b   = gm / N_TOK;
                const int tok = gm - b * N_TOK;
#pragma unroll
                for (int ni = 0; ni < 4; ++ni) {
                    const int gn    = bx * 128 + wn * 64 + ni * 16 + lm;
                    const int which = gn >> 10;
                    const int h     = (gn >> 6) & 15;
                    const int d     = gn & 63;
                    const size_t dst = (size_t)which * HEAD_SLAB +
                                       (((size_t)(b * H_ + h)) * N_TOK + tok) * 64 + d;
                    out[dst] = acc[mi][ni][r] + bias[gn];
                }
            }
        }
    }
}

// ---------------------------------------------------------------------------
// RoPE (fp32) + bf16 hi/lo split of q,k into dedicated slabs.
// q gets the 1/sqrt(D)=0.125 score scale folded in.
// ---------------------------------------------------------------------------
__global__ __launch_bounds__(256)
void rope_convert(const float* __restrict__ qf, const float* __restrict__ kf,
                  const float* __restrict__ sin_, const float* __restrict__ cos_,
                  unsigned short* __restrict__ qhi, unsigned short* __restrict__ qlo,
                  unsigned short* __restrict__ khi, unsigned short* __restrict__ klo)
{
    const int idx = blockIdx.x * 256 + threadIdx.x;
    const int total = B_ * H_ * N_TOK * 32;
    if (idx >= total) return;
    const int d   = idx & 31;
    const int tmp = idx >> 5;
    const int n   = tmp % N_TOK;
    const int bh  = tmp / N_TOK;

    const size_t base = ((size_t)bh * N_TOK + n) * 64;
    float q1 = qf[base + d], q2 = qf[base + d + 32];
    float k1 = kf[base + d], k2 = kf[base + d + 32];

    if (n >= PREFIX) {
        const int r = n - PREFIX;
        const float c1 = cos_[r * 64 + d];
        const float c2 = cos_[r * 64 + d + 32];
        const float s1 = sin_[r * 64 + d];
        const float s2 = sin_[r * 64 + d + 32];
        const float nq1 = q1 * c1 - q2 * s1;
        const float nq2 = q2 * c2 + q1 * s2;
        q1 = nq1; q2 = nq2;
        const float nk1 = k1 * c1 - k2 * s1;
        const float nk2 = k2 * c2 + k1 * s2;
        k1 = nk1; k2 = nk2;
    }
    q1 *= 0.125f; q2 *= 0.125f;

    unsigned short h;
    h = f2bf(q1); qhi[base + d]      = h; qlo[base + d]      = f2bf(q1 - bf2f(h));
    h = f2bf(q2); qhi[base + d + 32] = h; qlo[base + d + 32] = f2bf(q2 - bf2f(h));
    h = f2bf(k1); khi[base + d]      = h; klo[base + d]      = f2bf(k1 - bf2f(h));
    h = f2bf(k2); khi[base + d + 32] = h; klo[base + d + 32] = f2bf(k2 - bf2f(h));
}

// ---------------------------------------------------------------------------
// V: fp32 [bh][n][64] -> bf16-hi transposed [bh][64][VT_STRIDE].
// One block per (key-tile, bh); LDS-tiled transpose, coalesced both sides.
// ---------------------------------------------------------------------------
__global__ __launch_bounds__(256)
void v_transpose(const float* __restrict__ vf, unsigned short* __restrict__ vt)
{
    __shared__ float t[64][65];
    const int tid = threadIdx.x;
    const int kt0 = blockIdx.x * 64;
    const int bh  = blockIdx.y;
    const float* src = vf + (size_t)bh * N_TOK * 64;

#pragma unroll
    for (int p = 0; p < 4; ++p) {
        const int e   = p * 256 + tid;
        const int key = e >> 4;
        const int c4  = (e & 15) << 2;
        const int gk  = kt0 + key;
        float4 v = make_float4(0.f, 0.f, 0.f, 0.f);
        if (gk < N_TOK) v = *(const float4*)(src + (size_t)gk * 64 + c4);
        t[key][c4 + 0] = v.x;
        t[key][c4 + 1] = v.y;
        t[key][c4 + 2] = v.z;
        t[key][c4 + 3] = v.w;
    }
    __syncthreads();

    const int d  = tid >> 2;
    const int kb = (tid & 3) << 4;
    unsigned short buf[16];
#pragma unroll
    for (int j = 0; j < 16; ++j) buf[j] = f2bf(t[kb + j][d]);
    unsigned short* dst = vt + (size_t)bh * 64 * VT_STRIDE + (size_t)d * VT_STRIDE + kt0 + kb;
#pragma unroll
    for (int j = 0; j < 4; ++j)
        *(ushort4*)(dst + j * 4) = *(ushort4*)&buf[j * 4];
}

// ---------------------------------------------------------------------------
// MFMA flash attention v2. Block = (bh, 128-q-tile); 4 waves x 32 q-rows.
// Q hi/lo fragments from pre-split slabs straight into registers.
// K (hi+lo) and V^T (hi only) staged per 64-key tile via global_load_lds
// width-16; the bank-decorrelating XOR swizzle is applied to the SOURCE chunk
// index (dest must be wave-uniform base + lane*16). QK^T = 3 MFMAs (exact);
// PV = 1 MFMA (bf16 P x bf16 V). LDS = 8+8+8+16 = 40KB -> 4 blocks/CU.
// grid.x = bh so all q-tiles of one bh land on XCD bh%8 (K/V L2 reuse).
// ---------------------------------------------------------------------------
__global__ __launch_bounds__(256, 4)
void attn_mfma2(const unsigned short* __restrict__ qhi_g, const unsigned short* __restrict__ qlo_g,
                const unsigned short* __restrict__ khi_g, const unsigned short* __restrict__ klo_g,
                const unsigned short* __restrict__ vt_g,
                unsigned short* __restrict__ Ohi, unsigned short* __restrict__ Olo)
{
    __shared__ unsigned short Khl[64 * 64];   // K hi  [key][d], chunk-swizzled
    __shared__ unsigned short Kll[64 * 64];   // K lo
    __shared__ unsigned short Vtl[64 * 64];   // V^T hi [d][key], chunk-swizzled
    __shared__ unsigned short Pl[128 * 64];   // P [q][key], elementwise-swizzled

    const int tid  = threadIdx.x;
    const int wave = tid >> 6;
    const int lane = tid & 63;
    const int lm   = lane & 15;
    const int quad = lane >> 4;
    const int bh   = blockIdx.x;
    const int q0   = blockIdx.y * 128;
    const int b    = bh >> 4;
    const int h    = bh & 15;

    const unsigned short* Qh  = qhi_g + (size_t)bh * N_TOK * 64;
    const unsigned short* Ql  = qlo_g + (size_t)bh * N_TOK * 64;
    const unsigned short* Khb = khi_g + (size_t)bh * N_TOK * 64;
    const unsigned short* Klb = klo_g + (size_t)bh * N_TOK * 64;
    const unsigned short* Vtb = vt_g  + (size_t)bh * 64 * VT_STRIDE;

    // ---- Q fragments straight from pre-split slabs ----
    bf16x8 qh[2][2], ql[2][2];
#pragma unroll
    for (int rt = 0; rt < 2; ++rt) {
        int row = q0 + wave * 32 + rt * 16 + lm;
        if (row > N_TOK - 1) row = N_TOK - 1;
#pragma unroll
        for (int s = 0; s < 2; ++s) {
            const size_t off = (size_t)row * 64 + s * 32 + quad * 8;
            qh[rt][s] = *(const bf16x8*)&Qh[off];
            ql[rt][s] = *(const bf16x8*)&Ql[off];
        }
    }

    f32x4 o[2][4];
    float m_i[2][4], l_i[2][4];
#pragma unroll
    for (int rt = 0; rt < 2; ++rt)
#pragma unroll
        for (int r = 0; r < 4; ++r) {
            m_i[rt][r] = -FLT_MAX;
            l_i[rt][r] = 0.f;
            o[rt][r] = (f32x4){0.f, 0.f, 0.f, 0.f};
        }

    for (int kt = 0; kt < 17; ++kt) {
        const int kt0 = kt * 64;
        __syncthreads();   // prev tile's frag reads done

        // ---- stage K hi/lo + V^T hi via global_load_lds (source-swizzled) ----
#pragma unroll
        for (int pass = 0; pass < 2; ++pass) {
            const int t  = pass * 256 + tid;      // chunk index 0..511
            const int r  = t >> 3;                // tile row
            const int qs = t & 7;                 // stored chunk-in-row
            const int sw = (qs ^ (r & 7)) << 3;   // source elem offset in row
            const int ldsoff = (pass * 256 + wave * 64) * 8;  // wave-uniform
            const int gk = min(kt0 + r, N_TOK - 1);
            __builtin_amdgcn_global_load_lds(
                (__attribute__((address_space(1))) void*)(Khb + (size_t)gk * 64 + sw),
                (__attribute__((address_space(3))) void*)&Khl[ldsoff], 16, 0, 0);
            __builtin_amdgcn_global_load_lds(
                (__attribute__((address_space(1))) void*)(Klb + (size_t)gk * 64 + sw),
                (__attribute__((address_space(3))) void*)&Kll[ldsoff], 16, 0, 0);
            __builtin_amdgcn_global_load_lds(
                (__attribute__((address_space(1))) void*)(Vtb + (size_t)r * VT_STRIDE + kt0 + sw),
                (__attribute__((address_space(3))) void*)&Vtl[ldsoff], 16, 0, 0);
        }
        __syncthreads();   // vmcnt drained by barrier semantics

        // ---- QK^T: S[32 q][64 key] per wave ----
        f32x4 s_acc[2][4];
#pragma unroll
        for (int rt = 0; rt < 2; ++rt)
#pragma unroll
            for (int ct = 0; ct < 4; ++ct)
                s_acc[rt][ct] = (f32x4){0.f, 0.f, 0.f, 0.f};

#pragma unroll
        for (int ct = 0; ct < 4; ++ct) {
            const int krow = ct * 16 + lm;
#pragma unroll
            for (int s = 0; s < 2; ++s) {
                const int chunk = ((s * 4 + quad) ^ (krow & 7)) << 3;
                const bf16x8 kbh = *(const bf16x8*)&Khl[krow * 64 + chunk];
                const bf16x8 kbl = *(const bf16x8*)&Kll[krow * 64 + chunk];
#pragma unroll
                for (int rt = 0; rt < 2; ++rt) {
                    s_acc[rt][ct] = __builtin_amdgcn_mfma_f32_16x16x32_bf16(qh[rt][s], kbh, s_acc[rt][ct], 0, 0, 0);
                    s_acc[rt][ct] = __builtin_amdgcn_mfma_f32_16x16x32_bf16(qh[rt][s], kbl, s_acc[rt][ct], 0, 0, 0);
                    s_acc[rt][ct] = __builtin_amdgcn_mfma_f32_16x16x32_bf16(ql[rt][s], kbh, s_acc[rt][ct], 0, 0, 0);
                }
            }
        }

        // ---- mask OOB keys (last tile only) ----
        if (kt0 + 64 > N_TOK) {
#pragma unroll
            for (int ct = 0; ct < 4; ++ct) {
                if (kt0 + ct * 16 + lm >= N_TOK) {
#pragma unroll
                    for (int rt = 0; rt < 2; ++rt)
#pragma unroll
                        for (int r = 0; r < 4; ++r) s_acc[rt][ct][r] = -FLT_MAX;
                }
            }
        }

        // ---- online softmax + publish P ----
#pragma unroll
        for (int rt = 0; rt < 2; ++rt) {
#pragma unroll
            for (int r = 0; r < 4; ++r) {
                float mt = fmaxf(fmaxf(s_acc[rt][0][r], s_acc[rt][1][r]),
                                 fmaxf(s_acc[rt][2][r], s_acc[rt][3][r]));
                mt = fmaxf(mt, __shfl_xor(mt, 1));
                mt = fmaxf(mt, __shfl_xor(mt, 2));
                mt = fmaxf(mt, __shfl_xor(mt, 4));
                mt = fmaxf(mt, __shfl_xor(mt, 8));
                const float mnew  = fmaxf(m_i[rt][r], mt);
                const float alpha = __expf(m_i[rt][r] - mnew);
                float pv[4], rs = 0.f;
#pragma unroll
                for (int ct = 0; ct < 4; ++ct) {
                    pv[ct] = __expf(s_acc[rt][ct][r] - mnew);
                    rs += pv[ct];
                }
                rs += __shfl_xor(rs, 1);
                rs += __shfl_xor(rs, 2);
                rs += __shfl_xor(rs, 4);
                rs += __shfl_xor(rs, 8);
                l_i[rt][r] = l_i[rt][r] * alpha + rs;
                m_i[rt][r] = mnew;
#pragma unroll
                for (int dt = 0; dt < 4; ++dt) o[rt][dt][r] *= alpha;
                const int prow = wave * 32 + rt * 16 + quad * 4 + r;
#pragma unroll
                for (int ct = 0; ct < 4; ++ct) {
                    const int col = ct * 16 + lm;
                    const int idx = prow * 64 + ((((col >> 3) ^ (prow & 7)) << 3) | (col & 7));
                    Pl[idx] = f2bf(pv[ct]);
                }
            }
        }

        // ---- PV: o += P @ V^T  (wave-private P; V hi only -> 1 MFMA) ----
#pragma unroll
        for (int ks = 0; ks < 2; ++ks) {
            bf16x8 pf[2];
#pragma unroll
            for (int rt = 0; rt < 2; ++rt) {
                const int prow = wave * 32 + rt * 16 + lm;
                const int chunk = ((ks * 4 + quad) ^ (prow & 7)) << 3;
                pf[rt] = *(const bf16x8*)&Pl[prow * 64 + chunk];
            }
#pragma unroll
            for (int dt = 0; dt < 4; ++dt) {
                const int vrow = dt * 16 + lm;
                const int chunk = ((ks * 4 + quad) ^ (vrow & 7)) << 3;
                const bf16x8 vh = *(const bf16x8*)&Vtl[vrow * 64 + chunk];
#pragma unroll
                for (int rt = 0; rt < 2; ++rt)
                    o[rt][dt] = __builtin_amdgcn_mfma_f32_16x16x32_bf16(pf[rt], vh, o[rt][dt], 0, 0, 0);
            }
        }
    }

    // ---- epilogue: normalize, bf16 hi/lo split, store [B,N,H,D] ----
#pragma unroll
    for (int rt = 0; rt < 2; ++rt) {
#pragma unroll
        for (int r = 0; r < 4; ++r) {
            const int gq = q0 + wave * 32 + rt * 16 + quad * 4 + r;
            if (gq >= N_TOK) continue;
            const float inv = 1.0f / l_i[rt][r];
            const size_t base = (((size_t)(b * N_TOK + gq)) * H_ + h) * D_;
#pragma unroll
            for (int dt = 0; dt < 4; ++dt) {
                const float val = o[rt][dt][r] * inv;
                const unsigned short hb = f2bf(val);
                Ohi[base + dt * 16 + lm] = hb;
                Olo[base + dt * 16 + lm] = f2bf(val - bf2f(hb));
            }
        }
    }
}

// ---------------------------------------------------------------------------
// ws = EXACTLY 4 fp32 slabs (269,746,176 B — proven budget).
//   slab1: q fp32       -> attn_hi/attn_lo (after rope_convert)
//   slab2: k fp32       -> wp_hi/wp_lo     (after rope_convert)
//   slab3: v fp32       -> qhi/qlo         (after v_transpose)
//   slab4: x_hi/x_lo    -> khi/klo         (after GEMM1)
//   d_out: wq_hi/wq_lo (during GEMM1) -> vthi (35.7MB, until GEMM2 overwrites)
// ---------------------------------------------------------------------------
extern "C" void kernel_launch(void* const* d_in, const int* in_sizes, int n_in,
                              void* d_out, int out_size, void* d_ws, size_t ws_size,
                              hipStream_t stream)
{
    const float* x        = (const float*)d_in[0];
    const float* rope_sin = (const float*)d_in[1];
    const float* rope_cos = (const float*)d_in[2];
    const float* W_qkv    = (const float*)d_in[3];
    const float* b_qkv    = (const float*)d_in[4];
    const float* W_proj   = (const float*)d_in[5];
    const float* b_proj   = (const float*)d_in[6];
    float* out = (float*)d_out;

    float* q_buf = (float*)d_ws;
    float* k_buf = q_buf + HEAD_SLAB;
    float* v_buf = q_buf + 2 * HEAD_SLAB;
    float* slab4 = q_buf + 3 * HEAD_SLAB;

    unsigned short* x_hi = (unsigned short*)slab4;
    unsigned short* x_lo = x_hi + HEAD_SLAB;
    unsigned short* wq_hi = (unsigned short*)d_out;
    unsigned short* wq_lo = wq_hi + (size_t)3 * C_ * C_;

    unsigned short* vthi  = (unsigned short*)d_out;          // after GEMM1
    unsigned short* qhi   = (unsigned short*)v_buf;          // after v_transpose
    unsigned short* qlo   = qhi + HEAD_SLAB;
    unsigned short* khi   = (unsigned short*)slab4;          // after GEMM1
    unsigned short* klo   = khi + HEAD_SLAB;
    unsigned short* attn_hi = (unsigned short*)q_buf;        // after rope_convert
    unsigned short* attn_lo = attn_hi + HEAD_SLAB;
    unsigned short* wp_hi = (unsigned short*)k_buf;          // after rope_convert
    unsigned short* wp_lo = wp_hi + (size_t)C_ * C_;

    // 0) fp32 -> bf16 hi/lo splits for x and W_qkv
    {
        const int n4x = M_ROWS * C_ / 4;
        split_kernel<<<(n4x + 255) / 256, 256, 0, stream>>>(x, x_hi, x_lo, n4x);
        const int n4q = 3 * C_ * C_ / 4;
        split_kernel<<<(n4q + 255) / 256, 256, 0, stream>>>(W_qkv, wq_hi, wq_lo, n4q);
    }
    // 1) QKV projection (MFMA) -> q/k/v fp32 [B,H,N,D]
    {
        dim3 grid(3 * C_ / 128, (M_ROWS + 127) / 128);
        gemm_mfma<<<grid, 256, 0, stream>>>(x_hi, x_lo, wq_hi, wq_lo, b_qkv,
                                            q_buf, M_ROWS, 3 * C_, C_, 1);
    }
    // 2a) V -> bf16-hi transposed slab (in d_out; wq splits now dead)
    {
        dim3 grid(17, B_ * H_);
        v_transpose<<<grid, 256, 0, stream>>>(v_buf, vthi);
    }
    // 2b) RoPE + split q,k -> bf16 hi/lo slabs (v fp32 now dead)
    {
        const int total = B_ * H_ * N_TOK * 32;
        rope_convert<<<(total + 255) / 256, 256, 0, stream>>>(
            q_buf, k_buf, rope_sin, rope_cos, qhi, qlo, khi, klo);
    }
    // 3) MFMA flash attention -> attn hi/lo bf16 [B,N,H,D] (q fp32 dead)
    {
        dim3 grid(B_ * H_, (N_TOK + 127) / 128);   // x=bh: XCD locality
        attn_mfma2<<<grid, 256, 0, stream>>>(qhi, qlo, khi, klo, vthi,
                                             attn_hi, attn_lo);
    }
    // 3b) split W_proj into dead k-slab
    {
        const int n4p = C_ * C_ / 4;
        split_kernel<<<(n4p + 255) / 256, 256, 0, stream>>>(W_proj, wp_hi, wp_lo, n4p);
    }
    // 4) Output projection (MFMA) -> d_out (overwrites vthi; attn done)
    {
        dim3 grid(C_ / 128, (M_ROWS + 127) / 128);
        gemm_mfma<<<grid, 256, 0, stream>>>(attn_hi, attn_lo, wp_hi, wp_lo, b_proj,
                                            out, M_ROWS, C_, C_, 0);
    }
}